// Round 1
// baseline (471.862 us; speedup 1.0000x reference)
//
#include <hip/hip_runtime.h>
#include <hip/hip_bf16.h>
#include <cstddef>

#define N_NODES 50000
#define M_NBR   12
#define C_CH    128
#define F_DIM   64

// 1 / (sqrt(4*pi) * sqrt(C) * M)
constexpr float SCALE_CE =
    (float)(1.0 / (3.5449077018110318 * 11.313708498984761 * 12.0));

__device__ __forceinline__ float softplus_f(float x) {
    return fmaxf(x, 0.0f) + log1pf(expf(-fabsf(x)));
}

// Kernel A: per-edge radial scalar (MLP) + gather-aggregate -> g (stored in d_out)
// block = 256 (4 waves), each wave owns 2 nodes (12 edges each); 8 nodes/block.
__global__ __launch_bounds__(256) void kA(
    const float* __restrict__ atom_fea,
    const float* __restrict__ nbr_fea,
    const int*   __restrict__ nbr_idx,
    const float* __restrict__ w1,
    const float* __restrict__ b1,
    const float* __restrict__ w2,
    const float* __restrict__ b2,
    float* __restrict__ g)
{
    __shared__ float w1s[F_DIM * F_DIM];
    __shared__ float b1s[F_DIM];
    __shared__ float w2c[F_DIM];
    const int tid = threadIdx.x;
    #pragma unroll
    for (int t = 0; t < 4; ++t) {
        int idx = (tid + t * 256) * 4;
        *(float4*)&w1s[idx] = *(const float4*)&w1[idx];
    }
    if (tid < F_DIM) {
        b1s[tid] = b1[tid];
        w2c[tid] = w2[tid * 9];   // w2[:,0], row-major (F,9)
    }
    __syncthreads();

    const float b2_0 = b2[0];
    const int lane = tid & 63;
    const int wid  = tid >> 6;

    for (int n = 0; n < 2; ++n) {
        const int i = blockIdx.x * 8 + wid * 2 + n;
        float2 acc = make_float2(0.0f, 0.0f);
        for (int m = 0; m < M_NBR; ++m) {
            const int e = __builtin_amdgcn_readfirstlane(i * M_NBR + m);
            const float* row = nbr_fea + (size_t)e * F_DIM;
            float h = b1s[lane];
            #pragma unroll
            for (int kk = 0; kk < F_DIM; kk += 4) {
                float4 f = *(const float4*)(row + kk);   // wave-uniform address
                h = fmaf(f.x, w1s[(kk + 0) * F_DIM + lane], h);
                h = fmaf(f.y, w1s[(kk + 1) * F_DIM + lane], h);
                h = fmaf(f.z, w1s[(kk + 2) * F_DIM + lane], h);
                h = fmaf(f.w, w1s[(kk + 3) * F_DIM + lane], h);
            }
            float s = softplus_f(h) * w2c[lane];
            #pragma unroll
            for (int off = 32; off >= 1; off >>= 1)
                s += __shfl_xor(s, off);
            const float ce = (s + b2_0) * SCALE_CE;
            const int src = __builtin_amdgcn_readfirstlane(nbr_idx[e]);
            const float2 af = *(const float2*)(atom_fea + (size_t)src * C_CH + lane * 2);
            acc.x = fmaf(ce, af.x, acc.x);
            acc.y = fmaf(ce, af.y, acc.y);
        }
        *(float2*)(g + (size_t)i * C_CH + lane * 2) = acc;
    }
}

// Kernel B: x = atom_fea + g @ tp_w   (in-place on d_out, tile-wise safe)
// + per-block BatchNorm partial sums -> psum/psumsq
// block = 256, 64 rows per block; thread = (ty=tid/32 -> 8 rows, tx=tid%32 -> 4 cols)
__global__ __launch_bounds__(256) void kB(
    const float* __restrict__ g,         // == d_out
    const float* __restrict__ atom_fea,
    const float* __restrict__ tp_w,
    float* __restrict__ x,               // == d_out
    float* __restrict__ psum,
    float* __restrict__ psumsq)
{
    __shared__ float gl[64 * 128];       // 32 KiB
    const int tid = threadIdx.x;
    const int blk = blockIdx.x;
    const size_t base = (size_t)blk * 64 * 128;

    #pragma unroll
    for (int t = 0; t < 8; ++t) {
        int f = (tid + t * 256) * 4;
        int row = blk * 64 + (f >> 7);
        float4 v = make_float4(0.f, 0.f, 0.f, 0.f);
        if (row < N_NODES) v = *(const float4*)&g[base + f];
        *(float4*)&gl[f] = v;
    }
    __syncthreads();

    const int tx = tid & 31;
    const int ty = tid >> 5;
    const int col = tx * 4;

    float acc[8][4];
    #pragma unroll
    for (int r = 0; r < 8; ++r)
        #pragma unroll
        for (int c = 0; c < 4; ++c) acc[r][c] = 0.f;

    for (int k = 0; k < 128; ++k) {
        const float4 w = *(const float4*)&tp_w[k * 128 + col];
        #pragma unroll
        for (int r = 0; r < 8; ++r) {
            const float gv = gl[(ty * 8 + r) * 128 + k];   // broadcast within row-group
            acc[r][0] = fmaf(gv, w.x, acc[r][0]);
            acc[r][1] = fmaf(gv, w.y, acc[r][1]);
            acc[r][2] = fmaf(gv, w.z, acc[r][2]);
            acc[r][3] = fmaf(gv, w.w, acc[r][3]);
        }
    }
    __syncthreads();   // done with gl as g-tile; reuse as reduction buffer

    float ps[4]  = {0.f, 0.f, 0.f, 0.f};
    float pss[4] = {0.f, 0.f, 0.f, 0.f};
    #pragma unroll
    for (int r = 0; r < 8; ++r) {
        const int row = blk * 64 + ty * 8 + r;
        if (row < N_NODES) {
            const float4 a = *(const float4*)&atom_fea[(size_t)row * 128 + col];
            float4 xv;
            xv.x = a.x + acc[r][0];
            xv.y = a.y + acc[r][1];
            xv.z = a.z + acc[r][2];
            xv.w = a.w + acc[r][3];
            *(float4*)&x[(size_t)row * 128 + col] = xv;
            ps[0] += xv.x; ps[1] += xv.y; ps[2] += xv.z; ps[3] += xv.w;
            pss[0] += xv.x * xv.x; pss[1] += xv.y * xv.y;
            pss[2] += xv.z * xv.z; pss[3] += xv.w * xv.w;
        }
    }
    float* red = gl;   // [8][128] sums, [8][128] sumsq at +1024
    #pragma unroll
    for (int c = 0; c < 4; ++c) {
        red[ty * 128 + col + c]        = ps[c];
        red[1024 + ty * 128 + col + c] = pss[c];
    }
    __syncthreads();
    if (tid < 128) {
        float s = 0.f, ss2 = 0.f;
        #pragma unroll
        for (int t = 0; t < 8; ++t) {
            s   += red[t * 128 + tid];
            ss2 += red[1024 + t * 128 + tid];
        }
        psum[blk * 128 + tid]   = s;
        psumsq[blk * 128 + tid] = ss2;
    }
}

// Kernel C1: finalize mean / inv-std (single block, 128 threads)
__global__ void kC1(const float* __restrict__ psum,
                    const float* __restrict__ psumsq,
                    float* __restrict__ mean_o,
                    float* __restrict__ istd_o,
                    int nblocks)
{
    const int c = threadIdx.x;   // 0..127
    float s = 0.f, ss = 0.f;
    for (int b = 0; b < nblocks; ++b) {
        s  += psum[b * 128 + c];
        ss += psumsq[b * 128 + c];
    }
    const float m   = s / (float)N_NODES;
    const float var = ss / (float)N_NODES - m * m;
    mean_o[c] = m;
    istd_o[c] = rsqrtf(var + 1e-5f);
}

// Kernel C2: out = softplus(gamma * (x - mean) * istd + beta), in-place on d_out
__global__ __launch_bounds__(256) void kC2(
    float* __restrict__ x,
    const float* __restrict__ mean_i,
    const float* __restrict__ istd_i,
    const float* __restrict__ gamma,
    const float* __restrict__ beta)
{
    __shared__ float sm[128], si[128], sg[128], sb[128];
    const int tid = threadIdx.x;
    if (tid < 128) {
        sm[tid] = mean_i[tid];
        si[tid] = istd_i[tid];
        sg[tid] = gamma[tid];
        sb[tid] = beta[tid];
    }
    __syncthreads();
    const size_t idx = ((size_t)blockIdx.x * 256 + tid) * 4;
    const int c = (int)(idx & 127);
    float4 v = *(const float4*)&x[idx];
    float r[4] = {v.x, v.y, v.z, v.w};
    #pragma unroll
    for (int t = 0; t < 4; ++t) {
        const int cc = c + t;
        const float xn = (r[t] - sm[cc]) * si[cc];
        r[t] = softplus_f(fmaf(sg[cc], xn, sb[cc]));
    }
    v.x = r[0]; v.y = r[1]; v.z = r[2]; v.w = r[3];
    *(float4*)&x[idx] = v;
}

extern "C" void kernel_launch(void* const* d_in, const int* in_sizes, int n_in,
                              void* d_out, int out_size, void* d_ws, size_t ws_size,
                              hipStream_t stream)
{
    const float* atom_fea = (const float*)d_in[0];
    const float* nbr_fea  = (const float*)d_in[1];
    const int*   nbr_idx  = (const int*)d_in[2];
    // d_in[3] = pos : unused (only the l=0 SH component survives; it is constant)
    const float* w1       = (const float*)d_in[4];
    const float* b1       = (const float*)d_in[5];
    const float* w2       = (const float*)d_in[6];
    const float* b2       = (const float*)d_in[7];
    const float* tp_w     = (const float*)d_in[8];
    const float* bn_gamma = (const float*)d_in[9];
    const float* bn_beta  = (const float*)d_in[10];

    float* out = (float*)d_out;          // used as g, then x, then final out
    float* ws  = (float*)d_ws;

    const int nblocksB = (N_NODES + 63) / 64;          // 782
    float* psum   = ws;                                 // [782*128]
    float* psumsq = psum + (size_t)nblocksB * 128;      // [782*128]
    float* mean_b = psumsq + (size_t)nblocksB * 128;    // [128]
    float* istd_b = mean_b + 128;                       // [128]

    kA<<<N_NODES / 8, 256, 0, stream>>>(atom_fea, nbr_fea, nbr_idx,
                                        w1, b1, w2, b2, out);
    kB<<<nblocksB, 256, 0, stream>>>(out, atom_fea, tp_w, out, psum, psumsq);
    kC1<<<1, 128, 0, stream>>>(psum, psumsq, mean_b, istd_b, nblocksB);
    const int totalv4 = (N_NODES * C_CH) / 4;           // 1.6M float4
    kC2<<<totalv4 / 256, 256, 0, stream>>>(out, mean_b, istd_b, bn_gamma, bn_beta);
}

// Round 2
// 236.920 us; speedup vs baseline: 1.9916x; 1.9916x over previous
//
#include <hip/hip_runtime.h>
#include <hip/hip_bf16.h>
#include <cstddef>

#define N_NODES 50000
#define M_NBR   12
#define C_CH    128
#define F_DIM   64
#define E_EDGES (N_NODES * M_NBR)

// 1 / (sqrt(4*pi) * sqrt(C) * M)
constexpr float SCALE_CE =
    (float)(1.0 / (3.5449077018110318 * 11.313708498984761 * 12.0));

typedef __bf16 bf16x8 __attribute__((ext_vector_type(8)));
typedef float  f32x4  __attribute__((ext_vector_type(4)));

__device__ __forceinline__ float softplus_f(float x) {
    return fmaxf(x, 0.0f) + log1pf(expf(-fabsf(x)));
}

// Kernel A1: per-edge radial scalar via MFMA bf16.
// Wave = 16-edge tile. h(16x64) = nbr_fea(16x64) @ w1(64x64) via
// mfma_f32_16x16x32_bf16: 4 N-tiles x 2 K-steps. Epilogue: softplus, dot with
// w2[:,0], shfl-reduce over 16-lane column groups, write ce[e].
__global__ __launch_bounds__(256) void kA1(
    const float* __restrict__ nbr_fea,
    const float* __restrict__ w1,
    const float* __restrict__ b1,
    const float* __restrict__ w2,
    const float* __restrict__ b2,
    float* __restrict__ ce)
{
    const int tid   = threadIdx.x;
    const int lane  = tid & 63;
    const int wid   = tid >> 6;
    const int col16 = lane & 15;   // A: edge row; B/D: column within 16-tile
    const int kgrp  = lane >> 4;   // 0..3

    // B fragments: B[k][col] = w1[k*64 + col]; frag[n][ks][j] at
    // k = ks*32 + kgrp*8 + j, col = 16n + col16. Strided f32 loads (L2-hot).
    bf16x8 bfrag[4][2];
    #pragma unroll
    for (int n = 0; n < 4; ++n)
        #pragma unroll
        for (int ks = 0; ks < 2; ++ks)
            #pragma unroll
            for (int j = 0; j < 8; ++j)
                bfrag[n][ks][j] =
                    (__bf16)w1[(ks * 32 + kgrp * 8 + j) * F_DIM + 16 * n + col16];

    float b1v[4], w2v[4];
    #pragma unroll
    for (int n = 0; n < 4; ++n) {
        b1v[n] = b1[16 * n + col16];
        w2v[n] = w2[(16 * n + col16) * 9];   // w2[:,0], row-major (F,9)
    }
    const float b2_0 = b2[0];

    const int  tile = blockIdx.x * 4 + wid;
    const long e0   = (long)tile * 16;

    // A fragments: A[row][k] = nbr_fea[(e0+row)*64 + k]; row = col16,
    // k = ks*32 + kgrp*8 + j  -> 8 contiguous f32 per lane per K-step.
    const float* arow = nbr_fea + (e0 + col16) * F_DIM + kgrp * 8;
    bf16x8 afrag[2];
    #pragma unroll
    for (int ks = 0; ks < 2; ++ks) {
        float4 f0 = *(const float4*)(arow + ks * 32);
        float4 f1 = *(const float4*)(arow + ks * 32 + 4);
        afrag[ks][0] = (__bf16)f0.x; afrag[ks][1] = (__bf16)f0.y;
        afrag[ks][2] = (__bf16)f0.z; afrag[ks][3] = (__bf16)f0.w;
        afrag[ks][4] = (__bf16)f1.x; afrag[ks][5] = (__bf16)f1.y;
        afrag[ks][6] = (__bf16)f1.z; afrag[ks][7] = (__bf16)f1.w;
    }

    f32x4 acc[4];
    #pragma unroll
    for (int n = 0; n < 4; ++n) acc[n] = (f32x4){0.f, 0.f, 0.f, 0.f};
    #pragma unroll
    for (int ks = 0; ks < 2; ++ks)
        #pragma unroll
        for (int n = 0; n < 4; ++n)
            acc[n] = __builtin_amdgcn_mfma_f32_16x16x32_bf16(
                afrag[ks], bfrag[n][ks], acc[n], 0, 0, 0);

    // D layout: col = lane&15 (+16n), row(edge) = kgrp*4 + r
    float partial[4] = {0.f, 0.f, 0.f, 0.f};
    #pragma unroll
    for (int n = 0; n < 4; ++n)
        #pragma unroll
        for (int r = 0; r < 4; ++r) {
            const float h = acc[n][r] + b1v[n];
            partial[r] = fmaf(softplus_f(h), w2v[n], partial[r]);
        }
    #pragma unroll
    for (int r = 0; r < 4; ++r) {
        #pragma unroll
        for (int off = 1; off <= 8; off <<= 1)
            partial[r] += __shfl_xor(partial[r], off);
    }
    if (col16 == 0) {
        #pragma unroll
        for (int r = 0; r < 4; ++r)
            ce[e0 + kgrp * 4 + r] = (partial[r] + b2_0) * SCALE_CE;
    }
}

// Kernel A2: gather-aggregate g[i] = sum_m ce[e] * atom_fea[src[e]]
// One node per wave; lane owns 2 channels (float2).
__global__ __launch_bounds__(256) void kA2(
    const float* __restrict__ atom_fea,
    const int*   __restrict__ nbr_idx,
    const float* __restrict__ ce,
    float* __restrict__ g)
{
    const int tid  = threadIdx.x;
    const int lane = tid & 63;
    const int wid  = tid >> 6;
    const int i    = blockIdx.x * 4 + wid;
    const int eb   = i * M_NBR;

    float2 acc = make_float2(0.f, 0.f);
    #pragma unroll
    for (int m = 0; m < M_NBR; ++m) {
        const int   src = __builtin_amdgcn_readfirstlane(nbr_idx[eb + m]);
        const float cef = __uint_as_float(
            __builtin_amdgcn_readfirstlane(__float_as_uint(ce[eb + m])));
        const float2 af = *(const float2*)(atom_fea + (size_t)src * C_CH + lane * 2);
        acc.x = fmaf(cef, af.x, acc.x);
        acc.y = fmaf(cef, af.y, acc.y);
    }
    *(float2*)(g + (size_t)i * C_CH + lane * 2) = acc;
}

// Kernel B: x = atom_fea + g @ tp_w (in-place on d_out, tile-safe)
// + per-block BatchNorm partial sums.
__global__ __launch_bounds__(256) void kB(
    const float* __restrict__ g,
    const float* __restrict__ atom_fea,
    const float* __restrict__ tp_w,
    float* __restrict__ x,
    float* __restrict__ psum,
    float* __restrict__ psumsq)
{
    __shared__ float gl[64 * 128];
    const int tid = threadIdx.x;
    const int blk = blockIdx.x;
    const size_t base = (size_t)blk * 64 * 128;

    #pragma unroll
    for (int t = 0; t < 8; ++t) {
        int f = (tid + t * 256) * 4;
        int row = blk * 64 + (f >> 7);
        float4 v = make_float4(0.f, 0.f, 0.f, 0.f);
        if (row < N_NODES) v = *(const float4*)&g[base + f];
        *(float4*)&gl[f] = v;
    }
    __syncthreads();

    const int tx = tid & 31;
    const int ty = tid >> 5;
    const int col = tx * 4;

    float acc[8][4];
    #pragma unroll
    for (int r = 0; r < 8; ++r)
        #pragma unroll
        for (int c = 0; c < 4; ++c) acc[r][c] = 0.f;

    for (int k = 0; k < 128; ++k) {
        const float4 w = *(const float4*)&tp_w[k * 128 + col];
        #pragma unroll
        for (int r = 0; r < 8; ++r) {
            const float gv = gl[(ty * 8 + r) * 128 + k];
            acc[r][0] = fmaf(gv, w.x, acc[r][0]);
            acc[r][1] = fmaf(gv, w.y, acc[r][1]);
            acc[r][2] = fmaf(gv, w.z, acc[r][2]);
            acc[r][3] = fmaf(gv, w.w, acc[r][3]);
        }
    }
    __syncthreads();

    float ps[4]  = {0.f, 0.f, 0.f, 0.f};
    float pss[4] = {0.f, 0.f, 0.f, 0.f};
    #pragma unroll
    for (int r = 0; r < 8; ++r) {
        const int row = blk * 64 + ty * 8 + r;
        if (row < N_NODES) {
            const float4 a = *(const float4*)&atom_fea[(size_t)row * 128 + col];
            float4 xv;
            xv.x = a.x + acc[r][0];
            xv.y = a.y + acc[r][1];
            xv.z = a.z + acc[r][2];
            xv.w = a.w + acc[r][3];
            *(float4*)&x[(size_t)row * 128 + col] = xv;
            ps[0] += xv.x; ps[1] += xv.y; ps[2] += xv.z; ps[3] += xv.w;
            pss[0] += xv.x * xv.x; pss[1] += xv.y * xv.y;
            pss[2] += xv.z * xv.z; pss[3] += xv.w * xv.w;
        }
    }
    float* red = gl;
    #pragma unroll
    for (int c = 0; c < 4; ++c) {
        red[ty * 128 + col + c]        = ps[c];
        red[1024 + ty * 128 + col + c] = pss[c];
    }
    __syncthreads();
    if (tid < 128) {
        float s = 0.f, ss2 = 0.f;
        #pragma unroll
        for (int t = 0; t < 8; ++t) {
            s   += red[t * 128 + tid];
            ss2 += red[1024 + t * 128 + tid];
        }
        psum[blk * 128 + tid]   = s;
        psumsq[blk * 128 + tid] = ss2;
    }
}

// Kernel C1: finalize mean / inv-std. 1024 threads: 8 row-groups x 128 ch.
__global__ __launch_bounds__(1024) void kC1(
    const float* __restrict__ psum,
    const float* __restrict__ psumsq,
    float* __restrict__ mean_o,
    float* __restrict__ istd_o,
    int nblocks)
{
    __shared__ float red[2][8][128];
    const int t = threadIdx.x;
    const int c = t & 127;
    const int grp = t >> 7;
    float s = 0.f, ss = 0.f;
    for (int b = grp; b < nblocks; b += 8) {
        s  += psum[b * 128 + c];
        ss += psumsq[b * 128 + c];
    }
    red[0][grp][c] = s;
    red[1][grp][c] = ss;
    __syncthreads();
    if (t < 128) {
        float S = 0.f, SS = 0.f;
        #pragma unroll
        for (int k = 0; k < 8; ++k) { S += red[0][k][t]; SS += red[1][k][t]; }
        const float m   = S / (float)N_NODES;
        const float var = SS / (float)N_NODES - m * m;
        mean_o[t] = m;
        istd_o[t] = rsqrtf(var + 1e-5f);
    }
}

// Kernel C2: out = softplus(gamma * (x - mean) * istd + beta), in-place.
__global__ __launch_bounds__(256) void kC2(
    float* __restrict__ x,
    const float* __restrict__ mean_i,
    const float* __restrict__ istd_i,
    const float* __restrict__ gamma,
    const float* __restrict__ beta)
{
    __shared__ float sm[128], si[128], sg[128], sb[128];
    const int tid = threadIdx.x;
    if (tid < 128) {
        sm[tid] = mean_i[tid];
        si[tid] = istd_i[tid];
        sg[tid] = gamma[tid];
        sb[tid] = beta[tid];
    }
    __syncthreads();
    const size_t idx = ((size_t)blockIdx.x * 256 + tid) * 4;
    const int c = (int)(idx & 127);
    float4 v = *(const float4*)&x[idx];
    float r[4] = {v.x, v.y, v.z, v.w};
    #pragma unroll
    for (int t = 0; t < 4; ++t) {
        const int cc = c + t;
        const float xn = (r[t] - sm[cc]) * si[cc];
        r[t] = softplus_f(fmaf(sg[cc], xn, sb[cc]));
    }
    v.x = r[0]; v.y = r[1]; v.z = r[2]; v.w = r[3];
    *(float4*)&x[idx] = v;
}

extern "C" void kernel_launch(void* const* d_in, const int* in_sizes, int n_in,
                              void* d_out, int out_size, void* d_ws, size_t ws_size,
                              hipStream_t stream)
{
    const float* atom_fea = (const float*)d_in[0];
    const float* nbr_fea  = (const float*)d_in[1];
    const int*   nbr_idx  = (const int*)d_in[2];
    // d_in[3] = pos : unused (only the l=0 SH component survives; it is constant)
    const float* w1       = (const float*)d_in[4];
    const float* b1       = (const float*)d_in[5];
    const float* w2       = (const float*)d_in[6];
    const float* b2       = (const float*)d_in[7];
    const float* tp_w     = (const float*)d_in[8];
    const float* bn_gamma = (const float*)d_in[9];
    const float* bn_beta  = (const float*)d_in[10];

    float* out = (float*)d_out;
    float* ws  = (float*)d_ws;

    const int nblocksB = (N_NODES + 63) / 64;            // 782
    float* ce     = ws;                                   // [600000]
    float* psum   = ce + E_EDGES;                         // [782*128]
    float* psumsq = psum + (size_t)nblocksB * 128;        // [782*128]
    float* mean_b = psumsq + (size_t)nblocksB * 128;      // [128]
    float* istd_b = mean_b + 128;                         // [128]

    kA1<<<E_EDGES / 64, 256, 0, stream>>>(nbr_fea, w1, b1, w2, b2, ce);
    kA2<<<N_NODES / 4, 256, 0, stream>>>(atom_fea, nbr_idx, ce, out);
    kB<<<nblocksB, 256, 0, stream>>>(out, atom_fea, tp_w, out, psum, psumsq);
    kC1<<<1, 1024, 0, stream>>>(psum, psumsq, mean_b, istd_b, nblocksB);
    const int totalv4 = (N_NODES * C_CH) / 4;
    kC2<<<totalv4 / 256, 256, 0, stream>>>(out, mean_b, istd_b, bn_gamma, bn_beta);
}

// Round 3
// 157.185 us; speedup vs baseline: 3.0020x; 1.5073x over previous
//
#include <hip/hip_runtime.h>
#include <hip/hip_bf16.h>
#include <cstddef>

#define N_NODES 50000
#define M_NBR   12
#define C_CH    128
#define F_DIM   64
#define E_EDGES (N_NODES * M_NBR)
#define TILES_PER_WAVE 5

// 1 / (sqrt(4*pi) * sqrt(C) * M)
constexpr float SCALE_CE =
    (float)(1.0 / (3.5449077018110318 * 11.313708498984761 * 12.0));

typedef __bf16 bf16x8 __attribute__((ext_vector_type(8)));
typedef float  f32x4  __attribute__((ext_vector_type(4)));

// fast softplus: 2 HW transcendentals, no libm branches
__device__ __forceinline__ float softplus_f(float x) {
    return fmaxf(x, 0.0f) + __logf(1.0f + __expf(-fabsf(x)));
}

// Pre-kernel: build bf16 MFMA B-fragments of w1 into ws.
// frag[(n*2+ks)*64 + lane] (bf16x8): B[k][col]=w1[k*64+col],
// k = ks*32 + (lane>>4)*8 + j, col = 16n + (lane&15).
__global__ __launch_bounds__(512) void kW(
    const float* __restrict__ w1,
    __bf16* __restrict__ frag)
{
    const int t = threadIdx.x;           // 0..511
    const int lane = t & 63;
    const int f = t >> 6;                // n*2+ks
    const int n = f >> 1, ks = f & 1;
    const int col16 = lane & 15, kgrp = lane >> 4;
    bf16x8 v;
    #pragma unroll
    for (int j = 0; j < 8; ++j)
        v[j] = (__bf16)w1[(ks * 32 + kgrp * 8 + j) * F_DIM + 16 * n + col16];
    *(bf16x8*)&frag[(size_t)t * 8] = v;
}

// Kernel A1: per-edge radial scalar via MFMA bf16.
// Wave = 16-edge tile x TILES_PER_WAVE consecutive tiles.
__global__ __launch_bounds__(256) void kA1(
    const float* __restrict__ nbr_fea,
    const __bf16* __restrict__ frag,
    const float* __restrict__ b1,
    const float* __restrict__ w2,
    const float* __restrict__ b2,
    float* __restrict__ ce)
{
    const int tid   = threadIdx.x;
    const int lane  = tid & 63;
    const int wid   = tid >> 6;
    const int col16 = lane & 15;
    const int kgrp  = lane >> 4;

    bf16x8 bfrag[4][2];
    #pragma unroll
    for (int f = 0; f < 8; ++f)
        bfrag[f >> 1][f & 1] = *(const bf16x8*)&frag[((size_t)f * 64 + lane) * 8];

    float b1v[4], w2v[4];
    #pragma unroll
    for (int n = 0; n < 4; ++n) {
        b1v[n] = b1[16 * n + col16];
        w2v[n] = w2[(16 * n + col16) * 9];   // w2[:,0]
    }
    const float b2_0 = b2[0];

    const int tile0 = (blockIdx.x * 4 + wid) * TILES_PER_WAVE;

    for (int t = 0; t < TILES_PER_WAVE; ++t) {
        const long e0 = (long)(tile0 + t) * 16;
        const float* arow = nbr_fea + (e0 + col16) * F_DIM + kgrp * 8;

        bf16x8 afrag[2];
        #pragma unroll
        for (int ks = 0; ks < 2; ++ks) {
            float4 f0 = *(const float4*)(arow + ks * 32);
            float4 f1 = *(const float4*)(arow + ks * 32 + 4);
            afrag[ks][0] = (__bf16)f0.x; afrag[ks][1] = (__bf16)f0.y;
            afrag[ks][2] = (__bf16)f0.z; afrag[ks][3] = (__bf16)f0.w;
            afrag[ks][4] = (__bf16)f1.x; afrag[ks][5] = (__bf16)f1.y;
            afrag[ks][6] = (__bf16)f1.z; afrag[ks][7] = (__bf16)f1.w;
        }

        f32x4 acc[4];
        #pragma unroll
        for (int n = 0; n < 4; ++n) acc[n] = (f32x4){0.f, 0.f, 0.f, 0.f};
        #pragma unroll
        for (int ks = 0; ks < 2; ++ks)
            #pragma unroll
            for (int n = 0; n < 4; ++n)
                acc[n] = __builtin_amdgcn_mfma_f32_16x16x32_bf16(
                    afrag[ks], bfrag[n][ks], acc[n], 0, 0, 0);

        // D: col = lane&15 (+16n), row(edge) = kgrp*4 + r
        float partial[4] = {0.f, 0.f, 0.f, 0.f};
        #pragma unroll
        for (int n = 0; n < 4; ++n)
            #pragma unroll
            for (int r = 0; r < 4; ++r) {
                const float h = acc[n][r] + b1v[n];
                partial[r] = fmaf(softplus_f(h), w2v[n], partial[r]);
            }
        #pragma unroll
        for (int r = 0; r < 4; ++r) {
            #pragma unroll
            for (int off = 1; off <= 8; off <<= 1)
                partial[r] += __shfl_xor(partial[r], off);
        }
        if (col16 == 0) {
            #pragma unroll
            for (int r = 0; r < 4; ++r)
                ce[e0 + kgrp * 4 + r] = (partial[r] + b2_0) * SCALE_CE;
        }
    }
}

// Kernel AB: per 64-node block: (1) gather-aggregate g rows into LDS,
// (2) x = atom_fea + g @ tp_w (write d_out) + BN partial sums.
__global__ __launch_bounds__(256) void kAB(
    const float* __restrict__ atom_fea,
    const int*   __restrict__ nbr_idx,
    const float* __restrict__ ce,
    const float* __restrict__ tp_w,
    float* __restrict__ x,
    float* __restrict__ psum,
    float* __restrict__ psumsq)
{
    __shared__ float gl[64 * 128];
    const int tid  = threadIdx.x;
    const int lane = tid & 63;
    const int wid  = tid >> 6;
    const int blk  = blockIdx.x;

    // Phase 1: wave wid aggregates nodes wid*16 .. wid*16+15
    for (int t = 0; t < 16; ++t) {
        const int nl = wid * 16 + t;
        const int i  = blk * 64 + nl;
        float2 acc = make_float2(0.f, 0.f);
        if (i < N_NODES) {
            const int eb = i * M_NBR;
            int   idxv = 0;
            float cev  = 0.f;
            if (lane < M_NBR) {
                idxv = nbr_idx[eb + lane];
                cev  = ce[eb + lane];
            }
            #pragma unroll
            for (int m = 0; m < M_NBR; ++m) {
                const int   src = __shfl(idxv, m);
                const float c   = __shfl(cev, m);
                const float2 af = *(const float2*)(atom_fea + (size_t)src * C_CH + lane * 2);
                acc.x = fmaf(c, af.x, acc.x);
                acc.y = fmaf(c, af.y, acc.y);
            }
        }
        *(float2*)&gl[nl * 128 + lane * 2] = acc;
    }
    __syncthreads();

    // Phase 2: GEMM 64x128 @ 128x128 from LDS + BN partials
    const int tx = tid & 31;
    const int ty = tid >> 5;
    const int col = tx * 4;

    float acc[8][4];
    #pragma unroll
    for (int r = 0; r < 8; ++r)
        #pragma unroll
        for (int c = 0; c < 4; ++c) acc[r][c] = 0.f;

    for (int k = 0; k < 128; ++k) {
        const float4 w = *(const float4*)&tp_w[k * 128 + col];
        #pragma unroll
        for (int r = 0; r < 8; ++r) {
            const float gv = gl[(ty * 8 + r) * 128 + k];
            acc[r][0] = fmaf(gv, w.x, acc[r][0]);
            acc[r][1] = fmaf(gv, w.y, acc[r][1]);
            acc[r][2] = fmaf(gv, w.z, acc[r][2]);
            acc[r][3] = fmaf(gv, w.w, acc[r][3]);
        }
    }
    __syncthreads();

    float ps[4]  = {0.f, 0.f, 0.f, 0.f};
    float pss[4] = {0.f, 0.f, 0.f, 0.f};
    #pragma unroll
    for (int r = 0; r < 8; ++r) {
        const int row = blk * 64 + ty * 8 + r;
        if (row < N_NODES) {
            const float4 a = *(const float4*)&atom_fea[(size_t)row * 128 + col];
            float4 xv;
            xv.x = a.x + acc[r][0];
            xv.y = a.y + acc[r][1];
            xv.z = a.z + acc[r][2];
            xv.w = a.w + acc[r][3];
            *(float4*)&x[(size_t)row * 128 + col] = xv;
            ps[0] += xv.x; ps[1] += xv.y; ps[2] += xv.z; ps[3] += xv.w;
            pss[0] += xv.x * xv.x; pss[1] += xv.y * xv.y;
            pss[2] += xv.z * xv.z; pss[3] += xv.w * xv.w;
        }
    }
    float* red = gl;
    #pragma unroll
    for (int c = 0; c < 4; ++c) {
        red[ty * 128 + col + c]        = ps[c];
        red[1024 + ty * 128 + col + c] = pss[c];
    }
    __syncthreads();
    if (tid < 128) {
        float s = 0.f, ss2 = 0.f;
        #pragma unroll
        for (int t = 0; t < 8; ++t) {
            s   += red[t * 128 + tid];
            ss2 += red[1024 + t * 128 + tid];
        }
        psum[blk * 128 + tid]   = s;
        psumsq[blk * 128 + tid] = ss2;
    }
}

// Kernel C1: finalize mean / inv-std. 1024 threads: 8 row-groups x 128 ch.
__global__ __launch_bounds__(1024) void kC1(
    const float* __restrict__ psum,
    const float* __restrict__ psumsq,
    float* __restrict__ mean_o,
    float* __restrict__ istd_o,
    int nblocks)
{
    __shared__ float red[2][8][128];
    const int t = threadIdx.x;
    const int c = t & 127;
    const int grp = t >> 7;
    float s = 0.f, ss = 0.f;
    for (int b = grp; b < nblocks; b += 8) {
        s  += psum[b * 128 + c];
        ss += psumsq[b * 128 + c];
    }
    red[0][grp][c] = s;
    red[1][grp][c] = ss;
    __syncthreads();
    if (t < 128) {
        float S = 0.f, SS = 0.f;
        #pragma unroll
        for (int k = 0; k < 8; ++k) { S += red[0][k][t]; SS += red[1][k][t]; }
        const float m   = S / (float)N_NODES;
        const float var = SS / (float)N_NODES - m * m;
        mean_o[t] = m;
        istd_o[t] = rsqrtf(var + 1e-5f);
    }
}

// Kernel C2: out = softplus(gamma * (x - mean) * istd + beta), in-place.
__global__ __launch_bounds__(256) void kC2(
    float* __restrict__ x,
    const float* __restrict__ mean_i,
    const float* __restrict__ istd_i,
    const float* __restrict__ gamma,
    const float* __restrict__ beta)
{
    __shared__ float sm[128], si[128], sg[128], sb[128];
    const int tid = threadIdx.x;
    if (tid < 128) {
        sm[tid] = mean_i[tid];
        si[tid] = istd_i[tid];
        sg[tid] = gamma[tid];
        sb[tid] = beta[tid];
    }
    __syncthreads();
    const size_t idx = ((size_t)blockIdx.x * 256 + tid) * 4;
    const int c = (int)(idx & 127);
    float4 v = *(const float4*)&x[idx];
    float r[4] = {v.x, v.y, v.z, v.w};
    #pragma unroll
    for (int t = 0; t < 4; ++t) {
        const int cc = c + t;
        const float xn = (r[t] - sm[cc]) * si[cc];
        r[t] = softplus_f(fmaf(sg[cc], xn, sb[cc]));
    }
    v.x = r[0]; v.y = r[1]; v.z = r[2]; v.w = r[3];
    *(float4*)&x[idx] = v;
}

extern "C" void kernel_launch(void* const* d_in, const int* in_sizes, int n_in,
                              void* d_out, int out_size, void* d_ws, size_t ws_size,
                              hipStream_t stream)
{
    const float* atom_fea = (const float*)d_in[0];
    const float* nbr_fea  = (const float*)d_in[1];
    const int*   nbr_idx  = (const int*)d_in[2];
    // d_in[3] = pos : unused (only the l=0 SH component survives; it is constant)
    const float* w1       = (const float*)d_in[4];
    const float* b1       = (const float*)d_in[5];
    const float* w2       = (const float*)d_in[6];
    const float* b2       = (const float*)d_in[7];
    const float* tp_w     = (const float*)d_in[8];
    const float* bn_gamma = (const float*)d_in[9];
    const float* bn_beta  = (const float*)d_in[10];

    float* out = (float*)d_out;
    float* ws  = (float*)d_ws;

    const int nblocksB = (N_NODES + 63) / 64;            // 782
    float* ce     = ws;                                   // [600000]
    float* psum   = ce + E_EDGES;                         // [782*128]
    float* psumsq = psum + (size_t)nblocksB * 128;        // [782*128]
    float* mean_b = psumsq + (size_t)nblocksB * 128;      // [128]
    float* istd_b = mean_b + 128;                         // [128]
    __bf16* frag  = (__bf16*)(istd_b + 128);              // [4096] bf16 (8KB)

    kW<<<1, 512, 0, stream>>>(w1, frag);
    kA1<<<E_EDGES / (64 * TILES_PER_WAVE), 256, 0, stream>>>(
        nbr_fea, frag, b1, w2, b2, ce);
    kAB<<<nblocksB, 256, 0, stream>>>(atom_fea, nbr_idx, ce, tp_w,
                                      out, psum, psumsq);
    kC1<<<1, 1024, 0, stream>>>(psum, psumsq, mean_b, istd_b, nblocksB);
    const int totalv4 = (N_NODES * C_CH) / 4;
    kC2<<<totalv4 / 256, 256, 0, stream>>>(out, mean_b, istd_b, bn_gamma, bn_beta);
}

// Round 4
// 128.828 us; speedup vs baseline: 3.6627x; 1.2201x over previous
//
#include <hip/hip_runtime.h>
#include <hip/hip_bf16.h>
#include <cstddef>

#define N_NODES 50000
#define M_NBR   12
#define C_CH    128
#define F_DIM   64
#define E_EDGES (N_NODES * M_NBR)
#define TILES_PER_WAVE 5

// 1 / (sqrt(4*pi) * sqrt(C) * M)
constexpr float SCALE_CE =
    (float)(1.0 / (3.5449077018110318 * 11.313708498984761 * 12.0));

typedef __bf16 bf16x8 __attribute__((ext_vector_type(8)));
typedef float  f32x4  __attribute__((ext_vector_type(4)));

// fast softplus: 2 HW transcendentals, no libm branches
__device__ __forceinline__ float softplus_f(float x) {
    return fmaxf(x, 0.0f) + __logf(1.0f + __expf(-fabsf(x)));
}

__device__ __forceinline__ float bfhi_to_f(unsigned int p) {   // high 16 bits
    return __uint_as_float(p & 0xffff0000u);
}
__device__ __forceinline__ float bflo_to_f(unsigned int p) {   // low 16 bits
    return __uint_as_float(p << 16);
}

// Pre-kernel: build bf16 MFMA B-fragments for w1 (block 0) and tp_w (blocks 1-4).
// w1 frag  f = n*2+ks (n<4, ks<2): B[k][col]=w1[k*64+col],  k=ks*32+kgrp*8+j, col=16n+col16
// tp  frag f = n*4+ks (n<8, ks<4): B[k][col]=tp_w[k*128+col], same k pattern
__global__ __launch_bounds__(512) void kW(
    const float* __restrict__ w1,
    const float* __restrict__ tp_w,
    __bf16* __restrict__ fragW1,
    __bf16* __restrict__ fragTP)
{
    const int t = threadIdx.x;
    if (blockIdx.x == 0) {
        const int lane = t & 63;
        const int f = t >> 6;                 // n*2+ks
        const int n = f >> 1, ks = f & 1;
        const int col16 = lane & 15, kgrp = lane >> 4;
        bf16x8 v;
        #pragma unroll
        for (int j = 0; j < 8; ++j)
            v[j] = (__bf16)w1[(ks * 32 + kgrp * 8 + j) * F_DIM + 16 * n + col16];
        *(bf16x8*)&fragW1[(size_t)t * 8] = v;
    } else {
        const int fid = (blockIdx.x - 1) * 512 + t;   // 0..2047
        const int lane = fid & 63;
        const int f = fid >> 6;               // n*4+ks
        const int n = f >> 2, ks = f & 3;
        const int col16 = lane & 15, kgrp = lane >> 4;
        bf16x8 v;
        #pragma unroll
        for (int j = 0; j < 8; ++j)
            v[j] = (__bf16)tp_w[(ks * 32 + kgrp * 8 + j) * C_CH + 16 * n + col16];
        *(bf16x8*)&fragTP[(size_t)fid * 8] = v;
    }
}

// Kernel Y: y = atom_fea @ tp_w, bf16 MFMA, y stored bf16 (halves gather bytes).
// Wave = 16 rows; block = 4 waves = 64 rows. LDS-staged transpose for coalesced store.
__global__ __launch_bounds__(256) void kY(
    const float* __restrict__ atom_fea,
    const __bf16* __restrict__ fragTP,
    __bf16* __restrict__ y)
{
    __shared__ __bf16 yl[64 * 136];          // +8 pad: bank shift + 16B align
    const int tid   = threadIdx.x;
    const int lane  = tid & 63;
    const int wid   = tid >> 6;
    const int col16 = lane & 15;
    const int kgrp  = lane >> 4;

    const int row  = blockIdx.x * 64 + wid * 16 + col16;
    const int rowc = row < N_NODES ? row : N_NODES - 1;
    const float* ap = atom_fea + (size_t)rowc * C_CH + kgrp * 8;

    bf16x8 afrag[4];
    #pragma unroll
    for (int ks = 0; ks < 4; ++ks) {
        float4 f0 = *(const float4*)(ap + ks * 32);
        float4 f1 = *(const float4*)(ap + ks * 32 + 4);
        afrag[ks][0] = (__bf16)f0.x; afrag[ks][1] = (__bf16)f0.y;
        afrag[ks][2] = (__bf16)f0.z; afrag[ks][3] = (__bf16)f0.w;
        afrag[ks][4] = (__bf16)f1.x; afrag[ks][5] = (__bf16)f1.y;
        afrag[ks][6] = (__bf16)f1.z; afrag[ks][7] = (__bf16)f1.w;
    }

    #pragma unroll
    for (int n = 0; n < 8; ++n) {
        f32x4 acc = (f32x4){0.f, 0.f, 0.f, 0.f};
        #pragma unroll
        for (int ks = 0; ks < 4; ++ks) {
            bf16x8 bf = *(const bf16x8*)&fragTP[((size_t)(n * 4 + ks) * 64 + lane) * 8];
            acc = __builtin_amdgcn_mfma_f32_16x16x32_bf16(afrag[ks], bf, acc, 0, 0, 0);
        }
        // D: col = 16n+col16, row(local) = wid*16 + kgrp*4 + r
        #pragma unroll
        for (int r = 0; r < 4; ++r)
            yl[(wid * 16 + kgrp * 4 + r) * 136 + 16 * n + col16] = (__bf16)acc[r];
    }
    __syncthreads();

    #pragma unroll
    for (int it = 0; it < 4; ++it) {
        const int e  = it * 2048 + tid * 8;
        const int rw = e >> 7, cl = e & 127;
        const int grow = blockIdx.x * 64 + rw;
        if (grow < N_NODES) {
            bf16x8 v = *(const bf16x8*)&yl[rw * 136 + cl];
            *(bf16x8*)&y[(size_t)grow * C_CH + cl] = v;
        }
    }
}

// Kernel A1: per-edge radial scalar via MFMA bf16.
// Wave = 16-edge tile x TILES_PER_WAVE consecutive tiles.
__global__ __launch_bounds__(256) void kA1(
    const float* __restrict__ nbr_fea,
    const __bf16* __restrict__ frag,
    const float* __restrict__ b1,
    const float* __restrict__ w2,
    const float* __restrict__ b2,
    float* __restrict__ ce)
{
    const int tid   = threadIdx.x;
    const int lane  = tid & 63;
    const int wid   = tid >> 6;
    const int col16 = lane & 15;
    const int kgrp  = lane >> 4;

    bf16x8 bfrag[4][2];
    #pragma unroll
    for (int f = 0; f < 8; ++f)
        bfrag[f >> 1][f & 1] = *(const bf16x8*)&frag[((size_t)f * 64 + lane) * 8];

    float b1v[4], w2v[4];
    #pragma unroll
    for (int n = 0; n < 4; ++n) {
        b1v[n] = b1[16 * n + col16];
        w2v[n] = w2[(16 * n + col16) * 9];   // w2[:,0]
    }
    const float b2_0 = b2[0];

    const int tile0 = (blockIdx.x * 4 + wid) * TILES_PER_WAVE;

    for (int t = 0; t < TILES_PER_WAVE; ++t) {
        const long e0 = (long)(tile0 + t) * 16;
        const float* arow = nbr_fea + (e0 + col16) * F_DIM + kgrp * 8;

        bf16x8 afrag[2];
        #pragma unroll
        for (int ks = 0; ks < 2; ++ks) {
            float4 f0 = *(const float4*)(arow + ks * 32);
            float4 f1 = *(const float4*)(arow + ks * 32 + 4);
            afrag[ks][0] = (__bf16)f0.x; afrag[ks][1] = (__bf16)f0.y;
            afrag[ks][2] = (__bf16)f0.z; afrag[ks][3] = (__bf16)f0.w;
            afrag[ks][4] = (__bf16)f1.x; afrag[ks][5] = (__bf16)f1.y;
            afrag[ks][6] = (__bf16)f1.z; afrag[ks][7] = (__bf16)f1.w;
        }

        f32x4 acc[4];
        #pragma unroll
        for (int n = 0; n < 4; ++n) acc[n] = (f32x4){0.f, 0.f, 0.f, 0.f};
        #pragma unroll
        for (int ks = 0; ks < 2; ++ks)
            #pragma unroll
            for (int n = 0; n < 4; ++n)
                acc[n] = __builtin_amdgcn_mfma_f32_16x16x32_bf16(
                    afrag[ks], bfrag[n][ks], acc[n], 0, 0, 0);

        float partial[4] = {0.f, 0.f, 0.f, 0.f};
        #pragma unroll
        for (int n = 0; n < 4; ++n)
            #pragma unroll
            for (int r = 0; r < 4; ++r) {
                const float h = acc[n][r] + b1v[n];
                partial[r] = fmaf(softplus_f(h), w2v[n], partial[r]);
            }
        #pragma unroll
        for (int r = 0; r < 4; ++r) {
            #pragma unroll
            for (int off = 1; off <= 8; off <<= 1)
                partial[r] += __shfl_xor(partial[r], off);
        }
        if (col16 == 0) {
            #pragma unroll
            for (int r = 0; r < 4; ++r)
                ce[e0 + kgrp * 4 + r] = (partial[r] + b2_0) * SCALE_CE;
        }
    }
}

// Kernel G: x = atom_fea + sum_m ce * y[src]  (y bf16), + BN partial sums.
// Wave = 16 nodes sequential, lane owns channel pair {2*lane, 2*lane+1}.
// Next-node idx/ce prefetched to hide gather latency.
__global__ __launch_bounds__(256, 6) void kG(
    const float* __restrict__ atom_fea,
    const __bf16* __restrict__ y,
    const int*   __restrict__ nbr_idx,
    const float* __restrict__ ce,
    float* __restrict__ x,
    float* __restrict__ psum,
    float* __restrict__ psumsq)
{
    __shared__ float4 red[4][64];
    const int tid  = threadIdx.x;
    const int lane = tid & 63;
    const int wid  = tid >> 6;
    const int blk  = blockIdx.x;
    const int i0   = blk * 64 + wid * 16;

    float2 sum   = make_float2(0.f, 0.f);
    float2 sumsq = make_float2(0.f, 0.f);

    int   pidx = 0;
    float pce  = 0.f;
    if (i0 < N_NODES && lane < M_NBR) {
        pidx = nbr_idx[i0 * M_NBR + lane];
        pce  = ce[i0 * M_NBR + lane];
    }

    for (int t = 0; t < 16; ++t) {
        const int i = i0 + t;
        const int   cidx = pidx;
        const float cce  = pce;
        const int inext = i + 1;
        if (t < 15 && inext < N_NODES && lane < M_NBR) {
            pidx = nbr_idx[inext * M_NBR + lane];
            pce  = ce[inext * M_NBR + lane];
        }
        if (i < N_NODES) {
            float2 acc = make_float2(0.f, 0.f);
            #pragma unroll
            for (int m = 0; m < M_NBR; ++m) {
                const int   src = __shfl(cidx, m);
                const float c   = __shfl(cce, m);
                const unsigned int p =
                    *(const unsigned int*)(y + (size_t)src * C_CH + lane * 2);
                acc.x = fmaf(c, bflo_to_f(p), acc.x);
                acc.y = fmaf(c, bfhi_to_f(p), acc.y);
            }
            const float2 a = *(const float2*)(atom_fea + (size_t)i * C_CH + lane * 2);
            float2 xv = make_float2(a.x + acc.x, a.y + acc.y);
            *(float2*)(x + (size_t)i * C_CH + lane * 2) = xv;
            sum.x += xv.x; sum.y += xv.y;
            sumsq.x += xv.x * xv.x; sumsq.y += xv.y * xv.y;
        }
    }

    red[wid][lane] = make_float4(sum.x, sum.y, sumsq.x, sumsq.y);
    __syncthreads();
    if (tid < 128) {
        const int l = tid >> 1, comp = tid & 1;
        float s = 0.f, q = 0.f;
        #pragma unroll
        for (int w = 0; w < 4; ++w) {
            const float4 v = red[w][l];
            s += comp ? v.y : v.x;
            q += comp ? v.w : v.z;
        }
        psum[blk * 128 + tid]   = s;
        psumsq[blk * 128 + tid] = q;
    }
}

// Kernel C1: finalize mean / inv-std. 1024 threads: 8 row-groups x 128 ch.
__global__ __launch_bounds__(1024) void kC1(
    const float* __restrict__ psum,
    const float* __restrict__ psumsq,
    float* __restrict__ mean_o,
    float* __restrict__ istd_o,
    int nblocks)
{
    __shared__ float red[2][8][128];
    const int t = threadIdx.x;
    const int c = t & 127;
    const int grp = t >> 7;
    float s = 0.f, ss = 0.f;
    for (int b = grp; b < nblocks; b += 8) {
        s  += psum[b * 128 + c];
        ss += psumsq[b * 128 + c];
    }
    red[0][grp][c] = s;
    red[1][grp][c] = ss;
    __syncthreads();
    if (t < 128) {
        float S = 0.f, SS = 0.f;
        #pragma unroll
        for (int k = 0; k < 8; ++k) { S += red[0][k][t]; SS += red[1][k][t]; }
        const float m   = S / (float)N_NODES;
        const float var = SS / (float)N_NODES - m * m;
        mean_o[t] = m;
        istd_o[t] = rsqrtf(var + 1e-5f);
    }
}

// Kernel C2: out = softplus(gamma * (x - mean) * istd + beta), in-place.
__global__ __launch_bounds__(256) void kC2(
    float* __restrict__ x,
    const float* __restrict__ mean_i,
    const float* __restrict__ istd_i,
    const float* __restrict__ gamma,
    const float* __restrict__ beta)
{
    __shared__ float sm[128], si[128], sg[128], sb[128];
    const int tid = threadIdx.x;
    if (tid < 128) {
        sm[tid] = mean_i[tid];
        si[tid] = istd_i[tid];
        sg[tid] = gamma[tid];
        sb[tid] = beta[tid];
    }
    __syncthreads();
    const size_t idx = ((size_t)blockIdx.x * 256 + tid) * 4;
    const int c = (int)(idx & 127);
    float4 v = *(const float4*)&x[idx];
    float r[4] = {v.x, v.y, v.z, v.w};
    #pragma unroll
    for (int t = 0; t < 4; ++t) {
        const int cc = c + t;
        const float xn = (r[t] - sm[cc]) * si[cc];
        r[t] = softplus_f(fmaf(sg[cc], xn, sb[cc]));
    }
    v.x = r[0]; v.y = r[1]; v.z = r[2]; v.w = r[3];
    *(float4*)&x[idx] = v;
}

extern "C" void kernel_launch(void* const* d_in, const int* in_sizes, int n_in,
                              void* d_out, int out_size, void* d_ws, size_t ws_size,
                              hipStream_t stream)
{
    const float* atom_fea = (const float*)d_in[0];
    const float* nbr_fea  = (const float*)d_in[1];
    const int*   nbr_idx  = (const int*)d_in[2];
    // d_in[3] = pos : unused (only the l=0 SH component survives; it is constant)
    const float* w1       = (const float*)d_in[4];
    const float* b1       = (const float*)d_in[5];
    const float* w2       = (const float*)d_in[6];
    const float* b2       = (const float*)d_in[7];
    const float* tp_w     = (const float*)d_in[8];
    const float* bn_gamma = (const float*)d_in[9];
    const float* bn_beta  = (const float*)d_in[10];

    float* out = (float*)d_out;
    float* ws  = (float*)d_ws;

    const int nblocks = (N_NODES + 63) / 64;              // 782
    float* ce      = ws;                                   // [600000]
    float* psum    = ce + E_EDGES;                         // [782*128]
    float* psumsq  = psum + (size_t)nblocks * 128;         // [782*128]
    float* mean_b  = psumsq + (size_t)nblocks * 128;       // [128]
    float* istd_b  = mean_b + 128;                         // [128]
    __bf16* fragW1 = (__bf16*)(istd_b + 128);              // [4096]
    __bf16* fragTP = fragW1 + 4096;                        // [16384]
    __bf16* ybuf   = fragTP + 16384;                       // [50000*128] bf16 (12.8MB)

    kW<<<5, 512, 0, stream>>>(w1, tp_w, fragW1, fragTP);
    kY<<<nblocks, 256, 0, stream>>>(atom_fea, fragTP, ybuf);
    kA1<<<E_EDGES / (64 * TILES_PER_WAVE), 256, 0, stream>>>(
        nbr_fea, fragW1, b1, w2, b2, ce);
    kG<<<nblocks, 256, 0, stream>>>(atom_fea, ybuf, nbr_idx, ce,
                                    out, psum, psumsq);
    kC1<<<1, 1024, 0, stream>>>(psum, psumsq, mean_b, istd_b, nblocks);
    const int totalv4 = (N_NODES * C_CH) / 4;
    kC2<<<totalv4 / 256, 256, 0, stream>>>(out, mean_b, istd_b, bn_gamma, bn_beta);
}